// Round 8
// baseline (272.868 us; speedup 1.0000x reference)
//
#include <hip/hip_runtime.h>
#include <hip/hip_fp16.h>
#include <cstdint>
#include <cstddef>

// VideoSAGE: prep(weights) -> proj GEMM -> FUSED 3-layer GCN -> fused head.
// fp16 MFMA 16x16x32, fp32 accum.
// R5-R8 PM: tile-space + occupancy moves all bounced off ~20-29 B/cyc/CU
//   ingress in the 2-barrier structure; levers are BYTES.
// R9/R10 (WIN, 211->198): 64x256 tile, GCN halo-LDS band-blend (1x A traffic),
//   proj post-barrier A-prefetch.
// R11 PM: BN512 full-N single-pass proj: 198->202 (1 blk/CU exposure). Revert
//   proj to R9 geometry.
// R12: FUSE the 3 GCN layers into one kernel. Block = 96-row h-tile (64 out +
//   16 halo each side) x full H=512 in LDS (96KB, XOR-swizzled) + 32KB W slice
//   = 128KB LDS, 1 blk/CU, grid 256. 3 layers run entirely out of LDS: zero
//   intermediate global traffic (saves 67MB + 2 launches + 2/3 of A staging).
//   Halo contamination reach = 1 row/layer <= 3 << 16 margin; batch edges
//   protected by zero band coefs (cpf=0@s=0, cnf=0@s=S-1) as before.

typedef _Float16 f16;
typedef _Float16 f16x8 __attribute__((ext_vector_type(8)));
typedef float    f32x4 __attribute__((ext_vector_type(4)));

__device__ __forceinline__ void async_cp16(const void* g, void* l) {
  __builtin_amdgcn_global_load_lds((const __attribute__((address_space(1))) void*)g,
                                   (__attribute__((address_space(3))) void*)l, 16, 0, 0);
}

__device__ __forceinline__ f16x8 splat8(f16 v) {
  f16x8 r;
#pragma unroll
  for (int e = 0; e < 8; ++e) r[e] = v;
  return r;
}

// ---------------------------------------------------------------------------
// Proj GEMM: C[M,N] = A(fp32)*BT^T + bias, cvt fp32->f16 in A staging.
// R9-verified geometry: BM=64, BN=256, 512 thr (2x4 waves), grid (M/64, 2).
// ---------------------------------------------------------------------------
template<int BM, int BN, bool RELU, bool HAS_BIAS>
__global__ __launch_bounds__(512, 4) void proj_gemm_kernel(
    const float* __restrict__ Aptr, const f16* __restrict__ BT,
    f16* __restrict__ C, const float* __restrict__ bias,
    int M, int N, int K)
{
  constexpr int BK = 64;
  constexpr int NT = 512;
  constexpr int WAVES_N = 4;
  constexpr int WM = BM / 2;         // 32
  constexpr int WN = BN / WAVES_N;   // 64
  constexpr int TM = WM / 16;        // 2
  constexpr int TN = WN / 16;        // 4
  constexpr int ITER_B = (BN * BK) / (NT * 8);   // 4

  __shared__ __align__(16) f16 sA[BM * BK];
  __shared__ __align__(16) f16 sB[BN * BK];

  const int tid  = threadIdx.x;
  const int lane = tid & 63;
  const int wave = tid >> 6;
  const int wm   = wave / WAVES_N;
  const int wn   = wave % WAVES_N;
  const int m0   = blockIdx.x * BM;
  const int n0   = blockIdx.y * BN;
  const int quad = lane >> 4;
  const int l16  = lane & 15;

  uint32_t offA;
  {
    const int row = tid >> 3;
    const int q   = (tid & 7) ^ (row & 7);
    offA = (uint32_t)(((size_t)(m0 + row) * K + q * 8) * 4);
  }

  f32x4 acc[TM][TN];
#pragma unroll
  for (int i = 0; i < TM; ++i)
#pragma unroll
    for (int j = 0; j < TN; ++j)
      acc[i][j] = (f32x4){0.f, 0.f, 0.f, 0.f};

  float4 pa0, pa1;
  {
    const float4* p = (const float4*)((const char*)Aptr + offA);
    pa0 = p[0]; pa1 = p[1];
  }

  for (int kt = 0; kt < K; kt += BK) {
#pragma unroll
    for (int j = 0; j < ITER_B; ++j) {
      const int linear = j * NT + tid;
      const int row = linear >> 3;
      const int q   = (linear & 7) ^ (row & 7);
      async_cp16(BT + (size_t)(n0 + row) * K + kt + q * 8, &sB[linear * 8]);
    }
    {
      f16x8 o;
      o[0] = (f16)pa0.x; o[1] = (f16)pa0.y; o[2] = (f16)pa0.z; o[3] = (f16)pa0.w;
      o[4] = (f16)pa1.x; o[5] = (f16)pa1.y; o[6] = (f16)pa1.z; o[7] = (f16)pa1.w;
      *(f16x8*)&sA[(size_t)tid * 8] = o;
    }
    __syncthreads();   // barrier1

    if (kt + BK < K) {   // prefetch next A-regs; drains at barrier2
      const float4* p = (const float4*)((const char*)Aptr + (size_t)(kt + BK) * 4 + offA);
      pa0 = p[0]; pa1 = p[1];
    }

#pragma unroll
    for (int kk = 0; kk < 2; ++kk) {
      const int c = quad + kk * 4;
      f16x8 af[TM], bf[TN];
#pragma unroll
      for (int mi = 0; mi < TM; ++mi) {
        const int ml = wm * WM + mi * 16 + l16;
        af[mi] = *(const f16x8*)&sA[ml * 64 + ((c ^ (ml & 7)) * 8)];
      }
#pragma unroll
      for (int ni = 0; ni < TN; ++ni) {
        const int nl = wn * WN + ni * 16 + l16;
        bf[ni] = *(const f16x8*)&sB[nl * 64 + ((c ^ (nl & 7)) * 8)];
      }
#pragma unroll
      for (int mi = 0; mi < TM; ++mi)
#pragma unroll
        for (int ni = 0; ni < TN; ++ni)
          acc[mi][ni] = __builtin_amdgcn_mfma_f32_16x16x32_f16(
              af[mi], bf[ni], acc[mi][ni], 0, 0, 0);
    }
    __syncthreads();   // barrier2
  }

#pragma unroll
  for (int ni = 0; ni < TN; ++ni) {
    const int nc = n0 + wn * WN + ni * 16 + l16;
    const float bv = HAS_BIAS ? bias[nc] : 0.0f;
#pragma unroll
    for (int mi = 0; mi < TM; ++mi) {
#pragma unroll
      for (int r = 0; r < 4; ++r) {
        const int mr = m0 + wm * WM + mi * 16 + quad * 4 + r;
        float v = acc[mi][ni][r] + bv;
        if (RELU) v = fmaxf(v, 0.0f);
        C[(size_t)mr * N + nc] = (f16)v;
      }
    }
  }
}

// ---------------------------------------------------------------------------
// Fused 3-layer GCN: h_out = L3(relu(L2(relu(L1(h_in))))), each layer
// band(h) @ W_l + b_l. Block owns 64 output rows + 16-row halo each side.
// LDS: sh[96][512] f16 (96KB, chunk-XOR-swizzled) + sW[512][32] (32KB).
// 512 thr = 8 waves (2M x 4N): per wave 48 rows x 128 cols, TM=3, TN=8.
// ---------------------------------------------------------------------------
__global__ __launch_bounds__(512, 2) void gcn_fused_kernel(
    const f16* __restrict__ hin, const f16* __restrict__ GT,
    const float* __restrict__ gb, f16* __restrict__ hout, int M)
{
  constexpr int ROWS = 96, HALO = 16, BK = 32, S = 2048;
  constexpr int H = 512;
  constexpr int TM = 3, TN = 8;

  __shared__ __align__(16) f16 sh[ROWS * H];    // 96 KB
  __shared__ __align__(16) f16 sW[H * BK];      // 32 KB

  const int tid  = threadIdx.x;
  const int lane = tid & 63;
  const int wave = tid >> 6;
  const int wm   = wave >> 2;        // 0..1
  const int wn   = wave & 3;         // 0..3
  const int quad = lane >> 4;
  const int l16  = lane & 15;
  const int m0   = blockIdx.x * 64;

  const float dM = 0.57735026919f;   // (3+1e-8)^-1/2
  const float dE = 0.70710678118f;   // (2+1e-8)^-1/2

  // per-lane band coefs + clamped local row addresses for A-fragment rows
  f16 cf[TM][3];
  int rS[TM], rP[TM], rN[TM];        // local row of self/prev/next
#pragma unroll
  for (int mi = 0; mi < TM; ++mi) {
    const int lr = wm * 48 + mi * 16 + l16;     // 0..95
    const int g  = m0 - HALO + lr;              // may be out of [0,M)
    const int s  = g & (S - 1);
    const float dsv = (s == 0 || s == S - 1) ? dE : dM;
    cf[mi][0] = (f16)((s > 0)     ? dsv * ((s - 1 == 0) ? dE : dM)     : 0.0f);
    cf[mi][1] = (f16)(dsv * dsv);
    cf[mi][2] = (f16)((s < S - 1) ? dsv * ((s + 1 == S - 1) ? dE : dM) : 0.0f);
    rS[mi] = lr;
    rP[mi] = (lr > 0)        ? lr - 1 : 0;      // edge rows are garbage-
    rN[mi] = (lr < ROWS - 1) ? lr + 1 : ROWS-1; // tolerant (see header note)
  }

  // ---- stage h rows [m0-16, m0+80) (clamped), full 512 cols, swizzled ----
  // wave w, iter j stages row j*8+w; lane l -> chunk l, src chunk l^(row&7)
#pragma unroll
  for (int j = 0; j < 12; ++j) {
    const int row = j * 8 + wave;
    const int q   = lane ^ (row & 7) ^ (lane & ~63);   // lane<64: q = lane^(row&7) over 6 bits
    // NB: lane in 0..63, chunks per row = 64 -> chunk = lane, swizzle low 3 bits
    const int cin = lane;
    const int qq  = cin ^ (row & 7);
    int g = m0 - HALO + row;
    g = g < 0 ? 0 : (g >= M ? M - 1 : g);
    (void)q;
    async_cp16(hin + (size_t)g * H + qq * 8, &sh[((size_t)j * 512 + tid) * 8]);
  }

  for (int L = 0; L < 3; ++L) {
    const f16* WL = GT + (size_t)L * 262144;
    const float* bL = gb + L * 512;

    f32x4 acc[TM][TN];
#pragma unroll
    for (int i = 0; i < TM; ++i)
#pragma unroll
      for (int j = 0; j < TN; ++j)
        acc[i][j] = (f32x4){0.f, 0.f, 0.f, 0.f};

    for (int kt = 0; kt < H; kt += BK) {
      // stage W slice [512][kt:kt+32], 4 chunks/row, chunk-XOR-swizzled
#pragma unroll
      for (int j = 0; j < 4; ++j) {
        const int linear = j * 512 + tid;
        const int row = linear >> 2;
        const int cin = linear & 3;
        const int qq  = cin ^ (row & 3);
        async_cp16(WL + (size_t)row * H + kt + qq * 8, &sW[(size_t)linear * 8]);
      }
      __syncthreads();   // barrier1: sW ready (and sh on first step)

      const int cb = kt >> 3;
      f16x8 af[TM], bf[TN];
#pragma unroll
      for (int mi = 0; mi < TM; ++mi) {
        const int c = cb + quad;
        f16x8 pv = *(const f16x8*)&sh[rP[mi] * H + ((c ^ (rP[mi] & 7)) * 8)];
        f16x8 sv = *(const f16x8*)&sh[rS[mi] * H + ((c ^ (rS[mi] & 7)) * 8)];
        f16x8 nv = *(const f16x8*)&sh[rN[mi] * H + ((c ^ (rN[mi] & 7)) * 8)];
        f16x8 r = pv * splat8(cf[mi][0]);
        r += sv * splat8(cf[mi][1]);
        r += nv * splat8(cf[mi][2]);
        af[mi] = r;
      }
#pragma unroll
      for (int ni = 0; ni < TN; ++ni) {
        const int nl = wn * 128 + ni * 16 + l16;
        bf[ni] = *(const f16x8*)&sW[nl * BK + ((quad ^ (nl & 3)) * 8)];
      }
#pragma unroll
      for (int mi = 0; mi < TM; ++mi)
#pragma unroll
        for (int ni = 0; ni < TN; ++ni)
          acc[mi][ni] = __builtin_amdgcn_mfma_f32_16x16x32_f16(
              af[mi], bf[ni], acc[mi][ni], 0, 0, 0);
      __syncthreads();   // barrier2: sW consumed
    }

    // ---- epilogue ----
    if (L < 2) {
      // write relu(acc+bias) back into sh (in place; all reads done at b2)
#pragma unroll
      for (int ni = 0; ni < TN; ++ni) {
        const int nc = wn * 128 + ni * 16 + l16;
        const int chunk = nc >> 3;
        const float bv = bL[nc];
#pragma unroll
        for (int mi = 0; mi < TM; ++mi) {
#pragma unroll
          for (int r = 0; r < 4; ++r) {
            const int row = wm * 48 + mi * 16 + quad * 4 + r;
            const float v = fmaxf(acc[mi][ni][r] + bv, 0.0f);
            sh[row * H + ((chunk ^ (row & 7)) * 8) + (nc & 7)] = (f16)v;
          }
        }
      }
      // visibility ensured by next layer's barrier1 (after its first W stage)
    } else {
      // final layer: store rows 16..79 -> hout[m0 .. m0+64)
#pragma unroll
      for (int ni = 0; ni < TN; ++ni) {
        const int nc = wn * 128 + ni * 16 + l16;
        const float bv = bL[nc];
#pragma unroll
        for (int mi = 0; mi < TM; ++mi) {
#pragma unroll
          for (int r = 0; r < 4; ++r) {
            const int lr = wm * 48 + mi * 16 + quad * 4 + r;
            if (lr >= HALO && lr < HALO + 64) {
              const float v = acc[mi][ni][r] + bv;
              hout[(size_t)(m0 + lr - HALO) * H + nc] = (f16)v;
            }
          }
        }
      }
    }
  }
}

// ---------------------------------------------------------------------------
// Fused head, 32 rows/block (512 blocks): z1[32][256] LDS -> z2[32][128] LDS
// -> sigmoid dot. Total ~53.8KB -> 2 blocks/CU.
// ---------------------------------------------------------------------------
__global__ __launch_bounds__(256) void head_fused_kernel(
    const f16* __restrict__ h, const f16* __restrict__ S1T,
    const f16* __restrict__ S2T,
    const float* __restrict__ s1b, const float* __restrict__ s2b,
    const float* __restrict__ s3w, const float* __restrict__ s3b,
    float* __restrict__ out)
{
  __shared__ __align__(16) char smem[36864 + 32 * 264 * 2];
  f16* sA  = (f16*)smem;             // [32*64]   = 4KB
  f16* sB  = (f16*)(smem + 4096);    // [256*64]  = 32KB
  f16* zs  = (f16*)(smem + 36864);   // [32][264]
  f16* z2s = (f16*)smem;             // [32][136] = 8.5KB (reuses sA+sB head)
  f16* sB2 = (f16*)(smem + 8704);    // [128*64]  = 16KB

  const int tid  = threadIdx.x;
  const int lane = tid & 63;
  const int wave = tid >> 6;
  const int quad = lane >> 4;
  const int l16  = lane & 15;
  const int m0   = blockIdx.x * 32;

  // ---- GEMM1: z1[32][256] = relu(h[32x512] @ S1T^T + s1b); wave = 32x64 ----
  f32x4 acc[2][4];
#pragma unroll
  for (int i = 0; i < 2; ++i)
#pragma unroll
    for (int j = 0; j < 4; ++j) acc[i][j] = (f32x4){0.f, 0.f, 0.f, 0.f};

  for (int kt = 0; kt < 512; kt += 64) {
    __syncthreads();
    {   // A: 32x64 halfs = 256 chunks, 1 iter
      const int linear = tid;
      const int row = linear >> 3;
      const int q   = (linear & 7) ^ (row & 7);
      async_cp16(h + (size_t)(m0 + row) * 512 + kt + q * 8, &sA[linear * 8]);
    }
#pragma unroll
    for (int j = 0; j < 8; ++j) {   // B: 256x64 halfs = 2048 chunks
      const int linear = j * 256 + tid;
      const int row = linear >> 3;
      const int q   = (linear & 7) ^ (row & 7);
      async_cp16(S1T + (size_t)row * 512 + kt + q * 8, &sB[linear * 8]);
    }
    __syncthreads();
#pragma unroll
    for (int kk = 0; kk < 2; ++kk) {
      const int c = quad + kk * 4;
      f16x8 af[2], bf[4];
#pragma unroll
      for (int mi = 0; mi < 2; ++mi) {
        const int ml = mi * 16 + l16;
        af[mi] = *(const f16x8*)&sA[ml * 64 + ((c ^ (ml & 7)) * 8)];
      }
#pragma unroll
      for (int ni = 0; ni < 4; ++ni) {
        const int nl = wave * 64 + ni * 16 + l16;
        bf[ni] = *(const f16x8*)&sB[nl * 64 + ((c ^ (nl & 7)) * 8)];
      }
#pragma unroll
      for (int mi = 0; mi < 2; ++mi)
#pragma unroll
        for (int ni = 0; ni < 4; ++ni)
          acc[mi][ni] = __builtin_amdgcn_mfma_f32_16x16x32_f16(
              af[mi], bf[ni], acc[mi][ni], 0, 0, 0);
    }
  }
#pragma unroll
  for (int ni = 0; ni < 4; ++ni) {
    const int nc = wave * 64 + ni * 16 + l16;
    const float bv = s1b[nc];
#pragma unroll
    for (int mi = 0; mi < 2; ++mi)
#pragma unroll
      for (int r = 0; r < 4; ++r) {
        const int row = mi * 16 + quad * 4 + r;
        zs[row * 264 + nc] = (f16)fmaxf(acc[mi][ni][r] + bv, 0.0f);
      }
  }
  __syncthreads();

  // ---- GEMM2: z2[32][128] = relu(z1 @ S2T^T + s2b); wave = 32x32 ----
  f32x4 acc2[2][2];
#pragma unroll
  for (int i = 0; i < 2; ++i)
#pragma unroll
    for (int j = 0; j < 2; ++j) acc2[i][j] = (f32x4){0.f, 0.f, 0.f, 0.f};

  for (int kt2 = 0; kt2 < 4; ++kt2) {
    __syncthreads();
#pragma unroll
    for (int j = 0; j < 4; ++j) {   // B2: 128x64 halfs = 1024 chunks
      const int linear = j * 256 + tid;
      const int row = linear >> 3;
      const int q   = (linear & 7) ^ (row & 7);
      async_cp16(S2T + (size_t)row * 256 + kt2 * 64 + q * 8, &sB2[linear * 8]);
    }
    __syncthreads();
#pragma unroll
    for (int kk = 0; kk < 2; ++kk) {
      const int c = quad + kk * 4;
      f16x8 af[2], bf[2];
#pragma unroll
      for (int mi = 0; mi < 2; ++mi) {
        const int row = mi * 16 + l16;
        af[mi] = *(const f16x8*)&zs[row * 264 + (kt2 * 8 + c) * 8];
      }
#pragma unroll
      for (int ni = 0; ni < 2; ++ni) {
        const int nl = wave * 32 + ni * 16 + l16;
        bf[ni] = *(const f16x8*)&sB2[nl * 64 + ((c ^ (nl & 7)) * 8)];
      }
#pragma unroll
      for (int mi = 0; mi < 2; ++mi)
#pragma unroll
        for (int ni = 0; ni < 2; ++ni)
          acc2[mi][ni] = __builtin_amdgcn_mfma_f32_16x16x32_f16(
              af[mi], bf[ni], acc2[mi][ni], 0, 0, 0);
    }
  }
  __syncthreads();
#pragma unroll
  for (int ni = 0; ni < 2; ++ni) {
    const int nc = wave * 32 + ni * 16 + l16;
    const float bv = s2b[nc];
#pragma unroll
    for (int mi = 0; mi < 2; ++mi)
#pragma unroll
      for (int r = 0; r < 4; ++r) {
        const int row = mi * 16 + quad * 4 + r;
        z2s[row * 136 + nc] = (f16)fmaxf(acc2[mi][ni][r] + bv, 0.0f);
      }
  }
  __syncthreads();

  // ---- out[m] = sigmoid(dot(z2[m,:128], w) + b), 8 threads/row ----
  const int m  = tid >> 3;
  const int qd = tid & 7;
  float p = 0.f;
#pragma unroll
  for (int j = 0; j < 2; ++j) {
    f16x8 v = *(const f16x8*)&z2s[m * 136 + qd * 16 + j * 8];
#pragma unroll
    for (int e = 0; e < 8; ++e) p += (float)v[e] * s3w[qd * 16 + j * 8 + e];
  }
  p += __shfl_xor(p, 1);
  p += __shfl_xor(p, 2);
  p += __shfl_xor(p, 4);
  if (qd == 0) out[m0 + m] = 1.0f / (1.0f + expf(-(p + s3b[0])));
}

// ---------------------------------------------------------------------------
// Prep: 64x64 LDS tile-transposes of all weights (coalesced both sides).
// ---------------------------------------------------------------------------
__global__ __launch_bounds__(256) void prep_kernel(
    const float* __restrict__ Wp, f16* __restrict__ WpT,
    const float* __restrict__ gW, f16* __restrict__ GT,
    const float* __restrict__ s1W, f16* __restrict__ S1T,
    const float* __restrict__ s2W, f16* __restrict__ S2T)
{
  __shared__ f16 s[64 * 68];
  const int tid = threadIdx.x;
  int b = blockIdx.x;

  const float* W; f16* WT; int K, N, tile;
  if (b < 128)      { W = Wp;  WT = WpT; K = 1024; N = 512; tile = b; }
  else if (b < 320) { const int i = (b - 128) >> 6;
                      W = gW + (size_t)i * 262144; WT = GT + (size_t)i * 262144;
                      K = 512; N = 512; tile = (b - 128) & 63; }
  else if (b < 352) { W = s1W; WT = S1T; K = 512; N = 256; tile = b - 320; }
  else              { W = s2W; WT = S2T; K = 256; N = 128; tile = b - 352; }

  const int nt = tile % (N >> 6);
  const int kt = tile / (N >> 6);
#pragma unroll
  for (int it = 0; it < 16; ++it) {
    const int i  = it * 256 + tid;
    const int rk = i >> 6, rn = i & 63;
    s[rn * 68 + rk] = (f16)W[(size_t)(kt * 64 + rk) * N + nt * 64 + rn];
  }
  __syncthreads();
#pragma unroll
  for (int it = 0; it < 16; ++it) {
    const int i  = it * 256 + tid;
    const int rn = i >> 6, rk = i & 63;
    WT[(size_t)(nt * 64 + rn) * K + kt * 64 + rk] = s[rn * 68 + rk];
  }
}

// ---------------------------------------------------------------------------
extern "C" void kernel_launch(void* const* d_in, const int* in_sizes, int n_in,
                              void* d_out, int out_size, void* d_ws, size_t ws_size,
                              hipStream_t stream) {
  (void)in_sizes; (void)n_in; (void)out_size; (void)ws_size;
  const float* x   = (const float*)d_in[0];
  const float* Wp  = (const float*)d_in[1];
  const float* bp  = (const float*)d_in[2];
  const float* gW  = (const float*)d_in[3];
  const float* gb  = (const float*)d_in[4];
  const float* s1W = (const float*)d_in[5];
  const float* s1b = (const float*)d_in[6];
  const float* s2W = (const float*)d_in[7];
  const float* s2b = (const float*)d_in[8];
  const float* s3W = (const float*)d_in[9];
  const float* s3b = (const float*)d_in[10];
  float* out = (float*)d_out;

  constexpr int M = 16384;
  char* ws = (char*)d_ws;
  f16* hA  = (f16*)(ws + 0);            // 16384x512
  f16* hB  = (f16*)(ws + 16777216);     // 16384x512
  f16* WpT = (f16*)(ws + 33554432);     // [512,1024]
  f16* GT  = (f16*)(ws + 34603008);     // 3x[512,512]
  f16* S1T = (f16*)(ws + 36175872);     // [256,512]
  f16* S2T = (f16*)(ws + 36438016);     // [128,256]

  prep_kernel<<<360, 256, 0, stream>>>(Wp, WpT, gW, GT, s1W, S1T, s2W, S2T);

  // proj: hA = x @ Wp + bp  (R9-verified geometry)
  proj_gemm_kernel<64, 256, false, true>
      <<<dim3(M / 64, 2), 512, 0, stream>>>(x, WpT, hA, bp, M, 512, 1024);

  // fused 3-layer GCN: hB = GCN3(hA), all intermediates in LDS
  gcn_fused_kernel<<<M / 64, 512, 0, stream>>>(hA, GT, gb, hB, M);

  head_fused_kernel<<<M / 32, 256, 0, stream>>>(hB, S1T, S2T, s1b, s2b, s3W, s3b, out);
}